// Round 13
// baseline (729.264 us; speedup 1.0000x reference)
//
#include <hip/hip_runtime.h>
#include <hip/hip_bf16.h>
#include <math.h>

#define N_NODES 50000
#define N_EDGES 800000
#define NFEAT   256
#define NHID    128
#define ZDIM    32
#define N_PAIRS 10000

typedef __attribute__((ext_vector_type(8))) short bf16x8;
typedef __attribute__((ext_vector_type(4))) float f32x4;

// ---------------- row_ptr build (adj_row is sorted ascending) ----------------
__global__ void k_build_row_ptr(const int* __restrict__ row, int* __restrict__ row_ptr) {
    int e = blockIdx.x * blockDim.x + threadIdx.x;
    if (e >= N_EDGES) return;
    int cur  = row[e];
    int prev = (e == 0) ? -1 : row[e - 1];
    for (int r = prev + 1; r <= cur; ++r) row_ptr[r] = e;
    if (e == N_EDGES - 1) {
        for (int r = cur + 1; r <= N_NODES; ++r) row_ptr[r] = N_EDGES;
    }
}

// ---------------- pack a [K,128] f32 weight into MFMA B-frag order (bf16) ----
__global__ __launch_bounds__(256) void k_pack_gw(const float* __restrict__ W,
                                                 __hip_bfloat16* __restrict__ wpk) {
    int i  = blockIdx.x * 256 + threadIdx.x;
    int j  = i & 7;
    int l  = (i >> 3) & 63;
    int n  = (i >> 9) & 7;
    int kk = i >> 12;
    int d  = kk * 32 + (l >> 4) * 8 + j;
    int e  = n * 16 + (l & 15);
    wpk[i] = __float2bfloat16(W[(long)d * 128 + e]);
}

// ---------------- pack bil_w into B-frag order, SPLIT hi/lo bf16 ----------
__global__ __launch_bounds__(256) void k_pack_w2(const float* __restrict__ bw,
                                                 __hip_bfloat16* __restrict__ wh,
                                                 __hip_bfloat16* __restrict__ wl) {
    int i  = blockIdx.x * 256 + threadIdx.x;     // 0 .. 2^19-1
    int j  = i & 7;
    int l  = (i >> 3) & 63;
    int n  = (i >> 9) & 7;
    int kk = (i >> 12) & 3;
    int k  = i >> 14;
    int d  = kk * 32 + (l >> 4) * 8 + j;
    int e  = n * 16 + (l & 15);
    float w = bw[((long)k * 128 + d) * 128 + e];
    __hip_bfloat16 h = __float2bfloat16(w);
    wh[i] = h;
    wl[i] = __float2bfloat16(w - __bfloat162float(h));
}

// ---------------- dense GEMM via MFMA: Y[N,128] = X[N,K] @ W[K,128] (f32 out) -
// 256 threads = 4 waves; block = 64 rows; wave = 16 rows x 128 cols.
template <int K>
__global__ __launch_bounds__(256) void k_gemm_mfma(const float* __restrict__ X,
                                                   const __hip_bfloat16* __restrict__ wpk,
                                                   float* __restrict__ Y) {
    const int PAD = 8;
    __shared__ __hip_bfloat16 as[64][K + PAD];
    const int tid = threadIdx.x;
    const long r0 = (long)blockIdx.x * 64;

    const int QK = K / 4;
    for (int i = tid; i < 64 * QK; i += 256) {
        int row = i / QK, q = i - row * QK;
        float4 v = make_float4(0.f, 0.f, 0.f, 0.f);
        if (r0 + row < N_NODES)
            v = *reinterpret_cast<const float4*>(&X[(r0 + row) * (long)K + q * 4]);
        as[row][q * 4 + 0] = __float2bfloat16(v.x);
        as[row][q * 4 + 1] = __float2bfloat16(v.y);
        as[row][q * 4 + 2] = __float2bfloat16(v.z);
        as[row][q * 4 + 3] = __float2bfloat16(v.w);
    }
    __syncthreads();

    const int wrow = (tid >> 6) * 16;
    const int lane = tid & 63;
    const int l15  = lane & 15, l4 = lane >> 4;

    bf16x8 af[K / 32];
#pragma unroll
    for (int kk = 0; kk < K / 32; ++kk)
        af[kk] = *reinterpret_cast<const bf16x8*>(&as[wrow + l15][kk * 32 + l4 * 8]);

    f32x4 acc[8];
#pragma unroll
    for (int n = 0; n < 8; ++n) acc[n] = (f32x4){0.f, 0.f, 0.f, 0.f};

#pragma unroll 2
    for (int n = 0; n < 8; ++n) {
        f32x4 a = {0.f, 0.f, 0.f, 0.f};
#pragma unroll
        for (int kk = 0; kk < K / 32; ++kk) {
            bf16x8 wf = *reinterpret_cast<const bf16x8*>(&wpk[(((kk * 8 + n) * 64) + lane) * 8]);
            a = __builtin_amdgcn_mfma_f32_16x16x32_bf16(af[kk], wf, a, 0, 0, 0);
        }
        acc[n] = a;
    }

    // C/D layout: col = n*16 + (lane&15), row = wrow + (lane>>4)*4 + q
#pragma unroll
    for (int n = 0; n < 8; ++n)
#pragma unroll
        for (int q = 0; q < 4; ++q) {
            long row = r0 + wrow + l4 * 4 + q;
            if (row < N_NODES) Y[row * 128 + n * 16 + l15] = acc[n][q];
        }
}

// ---------------- sliced spmm + bias + relu (+ residual), f32 gather --------
// grid (node_blocks, 8 slices of 16 feats). 256 threads = 4 waves; wave = node.
// Wave = 4 x 16-lane edge-groups; in UNIFORM iteration u, group g handles edge
// 4u+g (converged shuffles; OOB edges contribute vi=0). Lane j reads one f32
// feat of the 16-feat slice -> 64B coalesced gather per edge.
// Per-slice gather working set = 50000*16*4 = 3.2 MB (fits 4 MB per-XCD L2).
template <bool HAS_RES>
__global__ __launch_bounds__(256) void k_spmm_slice(const float* __restrict__ H,
                                                    const int* __restrict__ row_ptr,
                                                    const int* __restrict__ col,
                                                    const float* __restrict__ val,
                                                    const float* __restrict__ bias,
                                                    const float* __restrict__ res,
                                                    float* __restrict__ out) {
    const int w    = threadIdx.x >> 6;
    const int lane = threadIdx.x & 63;
    const int r    = blockIdx.x * 4 + w;
    const int s    = blockIdx.y;            // feature slice 0..7 (16 feats)
    if (r >= N_NODES) return;
    const int g = lane >> 4;                // edge group 0..3
    const int j = lane & 15;                // feature within slice
    const int e0 = row_ptr[r], e1 = row_ptr[r + 1];

    float acc = 0.f;
    for (int base = e0; base < e1; base += 64) {
        int n = e1 - base; if (n > 64) n = 64;
        float v = 0.f; int c = 0;
        if (lane < n) { v = val[base + lane]; c = col[base + lane]; }
        const int nn = (n + 3) >> 2;        // wave-uniform trip count
        for (int u = 0; u < nn; ++u) {
            int i = u * 4 + g;              // <= 63 always; all lanes converged
            float vi = __shfl(v, i);        // OOB i -> source lane holds v=0
            int   ci = __shfl(c, i);
            acc += vi * H[(long)ci * 128 + s * 16 + j];
        }
    }
    // combine the 4 edge-groups (same dest node, same feature)
    acc += __shfl_xor(acc, 16);
    acc += __shfl_xor(acc, 32);

    if (g == 0) {
        const int f = s * 16 + j;
        acc = fmaxf(acc + bias[f], 0.f);
        if (HAS_RES) acc += res[(long)r * 128 + f];
        out[(long)r * 128 + f] = acc;
    }
}

// ---------------- bilinear decode via split-bf16 MFMA + fused MLP ----------------
__global__ __launch_bounds__(512, 4) void k_bilinear_mfma(const float* __restrict__ latent,
                                                          const int* __restrict__ idx0,
                                                          const int* __restrict__ idx1,
                                                          const __hip_bfloat16* __restrict__ wpk_hi,
                                                          const __hip_bfloat16* __restrict__ wpk_lo,
                                                          const float* __restrict__ bb,
                                                          const float* __restrict__ dw1,
                                                          const float* __restrict__ db1,
                                                          const float* __restrict__ dw2,
                                                          const float* __restrict__ db2,
                                                          float* __restrict__ pred) {
    __shared__ __hip_bfloat16 ah[32][136];   // a hi
    __shared__ __hip_bfloat16 al[32][136];   // a lo
    __shared__ float          bs[32][132];   // f32 b-rows (exact contraction)
    __shared__ float          fl[ZDIM][32];  // elu(feat), transposed [k][p]
    const int p0  = blockIdx.x * 32;
    const int tid = threadIdx.x;

    for (int i = tid; i < 32 * 32; i += 512) {
        int p = i >> 5, q = i & 31;
        int pi = p0 + p; if (pi >= N_PAIRS) pi = N_PAIRS - 1;
        const float4 av = *reinterpret_cast<const float4*>(&latent[(long)idx0[pi] * 128 + q * 4]);
        const float4 bv = *reinterpret_cast<const float4*>(&latent[(long)idx1[pi] * 128 + q * 4]);
        float a4[4] = {av.x, av.y, av.z, av.w};
#pragma unroll
        for (int t = 0; t < 4; ++t) {
            __hip_bfloat16 h = __float2bfloat16(a4[t]);
            ah[p][q * 4 + t] = h;
            al[p][q * 4 + t] = __float2bfloat16(a4[t] - __bfloat162float(h));
        }
        *reinterpret_cast<float4*>(&bs[p][q * 4]) = bv;
    }
    __syncthreads();

    const int wave = tid >> 6;          // 0..7  -> k = 4*wave + k2
    const int lane = tid & 63;
    const int l15  = lane & 15, l4 = lane >> 4;

    bf16x8 af[2][4];
#pragma unroll
    for (int M = 0; M < 2; ++M)
#pragma unroll
        for (int kk = 0; kk < 4; ++kk)
            af[M][kk] = *reinterpret_cast<const bf16x8*>(&ah[M * 16 + l15][kk * 32 + l4 * 8]);

#pragma unroll 1
    for (int k2 = 0; k2 < 4; ++k2) {
        const int k = wave * 4 + k2;
        float fsum[2][4];
#pragma unroll
        for (int M = 0; M < 2; ++M)
#pragma unroll
            for (int q = 0; q < 4; ++q) fsum[M][q] = 0.f;

#pragma unroll 1
        for (int n = 0; n < 8; ++n) {
            f32x4 acc0 = {0.f, 0.f, 0.f, 0.f};
            f32x4 acc1 = {0.f, 0.f, 0.f, 0.f};
#pragma unroll
            for (int kk = 0; kk < 4; ++kk) {
                const long ci = (((long)(k * 4 + kk) * 8 + n) * 512) + lane * 8;
                bf16x8 wh = *reinterpret_cast<const bf16x8*>(&wpk_hi[ci]);
                bf16x8 wl = *reinterpret_cast<const bf16x8*>(&wpk_lo[ci]);
                bf16x8 a0l = *reinterpret_cast<const bf16x8*>(&al[l15][kk * 32 + l4 * 8]);
                bf16x8 a1l = *reinterpret_cast<const bf16x8*>(&al[16 + l15][kk * 32 + l4 * 8]);
                acc0 = __builtin_amdgcn_mfma_f32_16x16x32_bf16(af[0][kk], wh, acc0, 0, 0, 0);
                acc0 = __builtin_amdgcn_mfma_f32_16x16x32_bf16(af[0][kk], wl, acc0, 0, 0, 0);
                acc0 = __builtin_amdgcn_mfma_f32_16x16x32_bf16(a0l,      wh, acc0, 0, 0, 0);
                acc1 = __builtin_amdgcn_mfma_f32_16x16x32_bf16(af[1][kk], wh, acc1, 0, 0, 0);
                acc1 = __builtin_amdgcn_mfma_f32_16x16x32_bf16(af[1][kk], wl, acc1, 0, 0, 0);
                acc1 = __builtin_amdgcn_mfma_f32_16x16x32_bf16(a1l,      wh, acc1, 0, 0, 0);
            }
#pragma unroll
            for (int q = 0; q < 4; ++q) {
                fsum[0][q] += acc0[q] * bs[l4 * 4 + q][n * 16 + l15];
                fsum[1][q] += acc1[q] * bs[16 + l4 * 4 + q][n * 16 + l15];
            }
        }

#pragma unroll
        for (int M = 0; M < 2; ++M) {
            float v0 = fsum[M][0], v1 = fsum[M][1], v2 = fsum[M][2], v3 = fsum[M][3];
#pragma unroll
            for (int off = 1; off < 16; off <<= 1) {
                v0 += __shfl_xor(v0, off);
                v1 += __shfl_xor(v1, off);
                v2 += __shfl_xor(v2, off);
                v3 += __shfl_xor(v3, off);
            }
            if (l15 == 0) {
                const float bbk = bb[k];
                float vv[4] = {v0, v1, v2, v3};
#pragma unroll
                for (int q = 0; q < 4; ++q) {
                    float v = vv[q] + bbk;
                    fl[k][M * 16 + l4 * 4 + q] = (v > 0.f) ? v : (expf(v) - 1.f);
                }
            }
        }
    }
    __syncthreads();

    if (tid < 32) {
        int p = p0 + tid;
        if (p < N_PAIRS) {
            float f[ZDIM];
#pragma unroll
            for (int k = 0; k < ZDIM; ++k) f[k] = fl[k][tid];
            float acc = db2[0];
            for (int j = 0; j < ZDIM; ++j) {
                float h = db1[j];
#pragma unroll
                for (int k = 0; k < ZDIM; ++k) h += f[k] * dw1[k * ZDIM + j];
                h = (h > 0.f) ? h : (expf(h) - 1.f);
                acc += h * dw2[j];
            }
            pred[p] = acc;
        }
    }
}

extern "C" void kernel_launch(void* const* d_in, const int* in_sizes, int n_in,
                              void* d_out, int out_size, void* d_ws, size_t ws_size,
                              hipStream_t stream) {
    const float* features = (const float*)d_in[0];
    const int*   adj_row  = (const int*)d_in[1];
    const int*   adj_col  = (const int*)d_in[2];
    const float* adj_val  = (const float*)d_in[3];
    const int*   idx      = (const int*)d_in[4];   // [2, N_PAIRS]
    const float* W0 = (const float*)d_in[5];
    const float* b0 = (const float*)d_in[6];
    const float* W1 = (const float*)d_in[7];
    const float* b1 = (const float*)d_in[8];
    const float* W2 = (const float*)d_in[9];
    const float* b2 = (const float*)d_in[10];
    const float* bil_w = (const float*)d_in[11];
    const float* bil_b = (const float*)d_in[12];
    const float* dw1 = (const float*)d_in[13];
    const float* db1 = (const float*)d_in[14];
    const float* dw2 = (const float*)d_in[15];
    const float* db2 = (const float*)d_in[16];

    float* pred   = (float*)d_out;                // [N_PAIRS]
    float* latent = (float*)d_out + N_PAIRS;      // [N_NODES,128]

    // workspace carve-up
    char* ws = (char*)d_ws;
    float* xw   = (float*)ws;                                 ws += (size_t)N_NODES * NHID * 4;
    float* xcur = (float*)ws;                                 ws += (size_t)N_NODES * NHID * 4;
    int*   row_ptr = (int*)ws;                                ws += (size_t)(N_NODES + 1) * 4;
    ws += 12;  // align following bf16 buffers to 16B
    __hip_bfloat16* wpk_hi = (__hip_bfloat16*)ws;             ws += (size_t)ZDIM * NHID * NHID * 2;
    __hip_bfloat16* wpk_lo = (__hip_bfloat16*)ws;             ws += (size_t)ZDIM * NHID * NHID * 2;
    __hip_bfloat16* w0pk = (__hip_bfloat16*)ws;               ws += (size_t)NFEAT * NHID * 2;
    __hip_bfloat16* w1pk = (__hip_bfloat16*)ws;               ws += (size_t)NHID * NHID * 2;
    __hip_bfloat16* w2pk = (__hip_bfloat16*)ws;               ws += (size_t)NHID * NHID * 2;

    const int*  idx0 = idx;
    const int*  idx1 = idx + N_PAIRS;

    k_build_row_ptr<<<(N_EDGES + 255) / 256, 256, 0, stream>>>(adj_row, row_ptr);
    k_pack_w2<<<(ZDIM * NHID * NHID) / 256, 256, 0, stream>>>(bil_w, wpk_hi, wpk_lo);
    k_pack_gw<<<(NFEAT * NHID) / 256, 256, 0, stream>>>(W0, w0pk);
    k_pack_gw<<<(NHID * NHID) / 256, 256, 0, stream>>>(W1, w1pk);
    k_pack_gw<<<(NHID * NHID) / 256, 256, 0, stream>>>(W2, w2pk);

    const int GB  = (N_NODES + 63) / 64;         // 782 blocks
    const dim3 SB((N_NODES + 3) / 4, 8);         // 12500 x 8 slices

    // layer 0
    k_gemm_mfma<NFEAT><<<GB, 256, 0, stream>>>(features, w0pk, xw);
    k_spmm_slice<false><<<SB, 256, 0, stream>>>(xw, row_ptr, adj_col, adj_val, b0, nullptr, xcur);

    // layer 1 (in-place residual)
    k_gemm_mfma<NHID><<<GB, 256, 0, stream>>>(xcur, w1pk, xw);
    k_spmm_slice<true><<<SB, 256, 0, stream>>>(xw, row_ptr, adj_col, adj_val, b1, xcur, xcur);

    // layer 2 -> latent in d_out
    k_gemm_mfma<NHID><<<GB, 256, 0, stream>>>(xcur, w2pk, xw);
    k_spmm_slice<true><<<SB, 256, 0, stream>>>(xw, row_ptr, adj_col, adj_val, b2, xcur, latent);

    // decode (bilinear + fused MLP)
    k_bilinear_mfma<<<(N_PAIRS + 31) / 32, 512, 0, stream>>>(latent, idx0, idx1, wpk_hi, wpk_lo,
                                                             bil_b, dw1, db1, dw2, db2, pred);
}